// Round 1
// baseline (325.369 us; speedup 1.0000x reference)
//
#include <hip/hip_runtime.h>
#include <hip/hip_bf16.h>
#include <stdint.h>

typedef __attribute__((ext_vector_type(8))) short s16x8;   // 8 x bf16 (4 VGPRs)
typedef __attribute__((ext_vector_type(4))) float f32x4;   // MFMA accumulator

union CvtI4 { int4 i; s16x8 s; };

__device__ __forceinline__ unsigned short f2bf(float f) {
    union { float f; unsigned u; } v; v.f = f;
    unsigned r = v.u + 0x7fffu + ((v.u >> 16) & 1u);   // round-to-nearest-even
    return (unsigned short)(r >> 16);
}

// ---------------------------------------------------------------------------
// Kernel 1: prep
//   xT[b][n][c]  = bf16( x[b][c][n] * sqrt(log2e/8) )   (Q/K operand, scaled)
//   vbf[b][c][n] = bf16( relu(bn1(w1 . x[b][:,n])) )    (V operand)
// ---------------------------------------------------------------------------
__global__ __launch_bounds__(256) void k_prep(
    const float* __restrict__ x, const float* __restrict__ w1,
    const float* __restrict__ g1, const float* __restrict__ b1,
    const float* __restrict__ m1, const float* __restrict__ v1,
    unsigned short* __restrict__ xT, unsigned short* __restrict__ vbf)
{
    const int b = blockIdx.x >> 4;
    const int n = ((blockIdx.x & 15) << 8) + threadIdx.x;
    const float QS = 0.42466090014400953f;   // sqrt(log2(e)/8)

    float xv[64];
    const float* xb = x + (size_t)b * (64 * 4096) + n;
#pragma unroll
    for (int c = 0; c < 64; ++c) xv[c] = xb[c * 4096];

    // transposed, scaled bf16 copy of x (Q and K both read this)
    unsigned* xtu = (unsigned*)xT + (size_t)(b * 4096 + n) * 32;
#pragma unroll
    for (int i = 0; i < 32; ++i) {
        unsigned lo = f2bf(xv[2 * i] * QS);
        unsigned hi = f2bf(xv[2 * i + 1] * QS);
        xtu[i] = lo | (hi << 16);
    }

    // V = relu(bn1(conv1x1(x)))
    unsigned short* vb = vbf + (size_t)b * (64 * 4096) + n;
#pragma unroll 2
    for (int o = 0; o < 64; ++o) {
        float inv = g1[o] * rsqrtf(v1[o] + 1e-5f);
        float sh  = b1[o] - m1[o] * inv;
        float acc = 0.f;
#pragma unroll
        for (int c = 0; c < 64; ++c) acc = fmaf(w1[o * 64 + c], xv[c], acc);
        float vv = fmaxf(fmaf(acc, inv, sh), 0.f);
        vb[o * 4096] = f2bf(vv);
    }
}

// ---------------------------------------------------------------------------
// Kernel 2: flash-style attention (no max subtraction; exp2 is safe in fp32)
//   out_attn[b][n][d] = sum_m exp2(S[n][m]) * V[d][m] / sum_m exp2(S[n][m])
// block = 256 thr (4 waves), 64 queries/block, m-tile = 128. grid = 8*64.
// ---------------------------------------------------------------------------
__global__ __launch_bounds__(256) void k_attn(
    const unsigned short* __restrict__ xT, const unsigned short* __restrict__ vbf,
    float* __restrict__ attn)
{
    __shared__ unsigned short Klds[128 * 72];       // [m][c]  pitch 72 (rows 16B-aligned)
    __shared__ unsigned short Vlds[64 * 136];       // [d][m]  pitch 136
    __shared__ unsigned short Plds[4][16 * 136];    // per-wave [n][m] pitch 136

    const int b    = blockIdx.x >> 6;
    const int n0   = (blockIdx.x & 63) << 6;
    const int tid  = threadIdx.x;
    const int wv   = tid >> 6;
    const int lane = tid & 63;
    const int quad = lane >> 4;
    const int l4   = lane & 15;

    // A-frags: 16 Q rows for this wave, loaded once from global (8 VGPRs total)
    const int4* qp = (const int4*)(xT + (size_t)((b << 12) + n0 + (wv << 4) + l4) * 64);
    CvtI4 ca0, ca1;
    ca0.i = qp[quad];        // c =      quad*8 .. +7
    ca1.i = qp[4 + quad];    // c = 32 + quad*8 .. +7
    const s16x8 A0 = ca0.s, A1 = ca1.s;

    f32x4 Oacc[4];
    float rs[4];
#pragma unroll
    for (int i = 0; i < 4; ++i) {
        Oacc[i] = (f32x4){0.f, 0.f, 0.f, 0.f};
        rs[i] = 0.f;
    }

    for (int mt = 0; mt < 32; ++mt) {
        const int m0 = mt << 7;
        __syncthreads();   // previous tile's LDS reads done before restage
        {   // stage K: 128 rows x 64 c (rows of xT, contiguous)
            const int mrow = tid >> 3, c8 = tid & 7;
#pragma unroll
            for (int it = 0; it < 4; ++it) {
                int m = (it << 5) + mrow;
                int4 d = *(const int4*)(xT + ((size_t)((b << 12) + m0 + m) << 6) + (c8 << 3));
                *(int4*)(Klds + m * 72 + (c8 << 3)) = d;
            }
        }
        {   // stage V: 64 rows x 128 m (contiguous in m)
            const int drow = tid >> 4, m16 = tid & 15;
#pragma unroll
            for (int it = 0; it < 4; ++it) {
                int d = (it << 4) + drow;
                int4 t = *(const int4*)(vbf + ((size_t)((b << 6) + d) << 12) + m0 + (m16 << 3));
                *(int4*)(Vlds + d * 136 + (m16 << 3)) = t;
            }
        }
        __syncthreads();

        unsigned short* Pw = Plds[wv];
        // S = Q.K^T (per 16-col subtile), P = exp2(S) -> LDS (A-layout source)
#pragma unroll
        for (int sub = 0; sub < 8; ++sub) {
            const unsigned short* kr = Klds + ((sub << 4) + l4) * 72 + (quad << 3);
            const s16x8 B0 = *(const s16x8*)(kr);
            const s16x8 B1 = *(const s16x8*)(kr + 32);
            f32x4 S = (f32x4){0.f, 0.f, 0.f, 0.f};
            S = __builtin_amdgcn_mfma_f32_16x16x32_bf16(A0, B0, S, 0, 0, 0);
            S = __builtin_amdgcn_mfma_f32_16x16x32_bf16(A1, B1, S, 0, 0, 0);
#pragma unroll
            for (int r = 0; r < 4; ++r) {
                float p = __builtin_amdgcn_exp2f(S[r]);
                rs[r] += p;   // row = quad*4+r, col = sub*16+l4
                Pw[((quad << 2) + r) * 136 + (sub << 4) + l4] = f2bf(p);
            }
        }
        // O += P . V^T   (A = P[n][m] from LDS, B = V[d][m] rows)
#pragma unroll
        for (int g = 0; g < 4; ++g) {
            const s16x8 Ap = *(const s16x8*)(Pw + l4 * 136 + (g << 5) + (quad << 3));
#pragma unroll
            for (int dt = 0; dt < 4; ++dt) {
                const s16x8 Bv = *(const s16x8*)(Vlds + ((dt << 4) + l4) * 136 + (g << 5) + (quad << 3));
                Oacc[dt] = __builtin_amdgcn_mfma_f32_16x16x32_bf16(Ap, Bv, Oacc[dt], 0, 0, 0);
            }
        }
    }

    // denominators: reduce row-sums across the 16 columns (low 4 lane bits)
#pragma unroll
    for (int r = 0; r < 4; ++r) {
        float v = rs[r];
        v += __shfl_xor(v, 1);
        v += __shfl_xor(v, 2);
        v += __shfl_xor(v, 4);
        v += __shfl_xor(v, 8);
        rs[r] = 1.0f / v;
    }

    // write attn[b][n][d] (n-major so epilogue reads channel vectors contiguously)
    float* orow = attn + (size_t)((b << 12) + n0 + (wv << 4)) * 64;
#pragma unroll
    for (int dt = 0; dt < 4; ++dt)
#pragma unroll
        for (int r = 0; r < 4; ++r)
            orow[((quad << 2) + r) * 64 + (dt << 4) + l4] = Oacc[dt][r] * rs[r];
}

// ---------------------------------------------------------------------------
// Kernel 3: dwconv3x3 + BN2 + ReLU + pointwise(w3) + BN3 + residual
// thread = one (h,w); t[64] channel accumulators in VGPRs.
// weights read via wave-uniform indices -> s_load (no LDS needed).
// ---------------------------------------------------------------------------
__global__ __launch_bounds__(256) void k_post(
    const float* __restrict__ attn, const float* __restrict__ x,
    const float* __restrict__ w2,
    const float* __restrict__ g2, const float* __restrict__ b2,
    const float* __restrict__ m2, const float* __restrict__ v2,
    const float* __restrict__ w3,
    const float* __restrict__ g3, const float* __restrict__ b3,
    const float* __restrict__ m3, const float* __restrict__ v3,
    float* __restrict__ out)
{
    const int b = blockIdx.x >> 4;
    const int h = ((blockIdx.x & 15) << 2) + (threadIdx.x >> 6);
    const int w = threadIdx.x & 63;

    float t[64];
#pragma unroll
    for (int c = 0; c < 64; ++c) t[c] = 0.f;

    const float* ab = attn + (size_t)(b << 12) * 64;
#pragma unroll
    for (int ky = 0; ky < 3; ++ky) {
        int hh = h + ky - 1;
        if (hh < 0 || hh > 63) continue;
#pragma unroll
        for (int kx = 0; kx < 3; ++kx) {
            int ww = w + kx - 1;
            if (ww < 0 || ww > 63) continue;
            const float4* ap = (const float4*)(ab + (size_t)((hh << 6) + ww) * 64);
            const int k = ky * 3 + kx;
#pragma unroll
            for (int i = 0; i < 16; ++i) {
                float4 a = ap[i];
                t[4 * i + 0] = fmaf(w2[(4 * i + 0) * 9 + k], a.x, t[4 * i + 0]);
                t[4 * i + 1] = fmaf(w2[(4 * i + 1) * 9 + k], a.y, t[4 * i + 1]);
                t[4 * i + 2] = fmaf(w2[(4 * i + 2) * 9 + k], a.z, t[4 * i + 2]);
                t[4 * i + 3] = fmaf(w2[(4 * i + 3) * 9 + k], a.w, t[4 * i + 3]);
            }
        }
    }
#pragma unroll
    for (int c = 0; c < 64; ++c) {
        float inv = g2[c] * rsqrtf(v2[c] + 1e-5f);
        float sh  = b2[c] - m2[c] * inv;
        t[c] = fmaxf(fmaf(t[c], inv, sh), 0.f);
    }

    const int n = (h << 6) + w;
    float* ob       = out + (size_t)(b << 6) * 4096 + n;
    const float* xr = x   + (size_t)(b << 6) * 4096 + n;
#pragma unroll 2
    for (int o = 0; o < 64; ++o) {
        float inv = g3[o] * rsqrtf(v3[o] + 1e-5f);
        float sh  = b3[o] - m3[o] * inv;
        float acc = 0.f;
#pragma unroll
        for (int c = 0; c < 64; ++c) acc = fmaf(w3[o * 64 + c], t[c], acc);
        ob[o * 4096] = fmaf(acc, inv, sh) + xr[o * 4096];
    }
}

// ---------------------------------------------------------------------------
extern "C" void kernel_launch(void* const* d_in, const int* in_sizes, int n_in,
                              void* d_out, int out_size, void* d_ws, size_t ws_size,
                              hipStream_t stream)
{
    const float* x  = (const float*)d_in[0];
    const float* w1 = (const float*)d_in[1];
    const float* g1 = (const float*)d_in[2];
    const float* b1 = (const float*)d_in[3];
    const float* m1 = (const float*)d_in[4];
    const float* v1 = (const float*)d_in[5];
    const float* w2 = (const float*)d_in[6];
    const float* g2 = (const float*)d_in[7];
    const float* b2 = (const float*)d_in[8];
    const float* m2 = (const float*)d_in[9];
    const float* v2 = (const float*)d_in[10];
    const float* w3 = (const float*)d_in[11];
    const float* g3 = (const float*)d_in[12];
    const float* b3 = (const float*)d_in[13];
    const float* m3 = (const float*)d_in[14];
    const float* v3 = (const float*)d_in[15];
    float* out = (float*)d_out;

    // workspace: xT bf16 4MB | vbf bf16 4MB | attn fp32 8MB  (= 16 MB total)
    unsigned short* xT  = (unsigned short*)d_ws;
    unsigned short* vbf = (unsigned short*)((char*)d_ws + (4u << 20));
    float*          attn = (float*)((char*)d_ws + (8u << 20));

    k_prep<<<128, 256, 0, stream>>>(x, w1, g1, b1, m1, v1, xT, vbf);
    k_attn<<<512, 256, 0, stream>>>(xT, vbf, attn);
    k_post<<<128, 256, 0, stream>>>(attn, x, w2, g2, b2, m2, v2,
                                    w3, g3, b3, m3, v3, out);
}

// Round 2
// 272.574 us; speedup vs baseline: 1.1937x; 1.1937x over previous
//
#include <hip/hip_runtime.h>
#include <stdint.h>

typedef __attribute__((ext_vector_type(8))) short s16x8;   // 8 x bf16
typedef __attribute__((ext_vector_type(4))) float f32x4;   // MFMA acc

union CvtI4 { int4 i; s16x8 s; };

__device__ __forceinline__ unsigned f2bf(float f) {
    union { float f; unsigned u; } v; v.f = f;
    return (v.u + 0x7fffu + ((v.u >> 16) & 1u)) >> 16;     // RNE, low 16 bits valid
}

// ---------------------------------------------------------------------------
// k_prep: per (b, 64-col chunk): LDS-transpose x tile ->
//   xT[b][n][c] = bf16(x * sqrt(log2e/8))  (coalesced 16B stores)
//   vbf[b][c][n] = bf16(relu(bn1(w1 . x)))
// grid 512 x 256
// ---------------------------------------------------------------------------
__global__ __launch_bounds__(256) void k_prep(
    const float* __restrict__ x, const float* __restrict__ w1,
    const float* __restrict__ g1, const float* __restrict__ b1,
    const float* __restrict__ m1, const float* __restrict__ v1,
    unsigned short* __restrict__ xT, unsigned short* __restrict__ vbf)
{
    __shared__ float X[64 * 65];   // [c][n] pad+1
    const int b  = blockIdx.x >> 6;
    const int n0 = (blockIdx.x & 63) << 6;
    const int tid = threadIdx.x;
    const float QS = 0.42466090014400953f;   // sqrt(log2(e)/8)

    {   // coalesced load: wave = one c row, lanes = n
        const int r = tid >> 6, nn = tid & 63;
        const float* xb = x + (size_t)b * 262144 + n0 + nn;
#pragma unroll
        for (int cc = 0; cc < 16; ++cc) {
            int c = cc * 4 + r;
            X[c * 65 + nn] = xb[(size_t)c * 4096];
        }
    }
    __syncthreads();

    {   // xT: 8 threads cover one 128B row -> fully coalesced int4 stores
        const int n8 = tid >> 3, c8 = tid & 7;
#pragma unroll
        for (int p = 0; p < 2; ++p) {
            int n = p * 32 + n8;
            unsigned u[4];
#pragma unroll
            for (int j = 0; j < 4; ++j) {
                unsigned lo = f2bf(X[(c8 * 8 + 2 * j) * 65 + n] * QS);
                unsigned hi = f2bf(X[(c8 * 8 + 2 * j + 1) * 65 + n] * QS);
                u[j] = lo | (hi << 16);
            }
            uint4 pk; pk.x = u[0]; pk.y = u[1]; pk.z = u[2]; pk.w = u[3];
            *(uint4*)(xT + (((size_t)((b << 12) + n0 + n)) << 6) + (c8 << 3)) = pk;
        }
    }

    {   // V = relu(bn1(conv1x1)): thread = (n, 16-channel group)
        const int n = tid & 63, og = tid >> 6;
        float rX[64];
#pragma unroll
        for (int c = 0; c < 64; ++c) rX[c] = X[c * 65 + n];
        unsigned short* vb = vbf + (((size_t)(b << 6)) << 12) + n0 + n;
#pragma unroll 2
        for (int oo = 0; oo < 16; ++oo) {
            int o = og * 16 + oo;
            float inv = g1[o] * rsqrtf(v1[o] + 1e-5f);
            float sh  = b1[o] - m1[o] * inv;
            float acc = 0.f;
#pragma unroll
            for (int c = 0; c < 64; ++c) acc = fmaf(w1[o * 64 + c], rX[c], acc);
            vb[(size_t)o << 12] = (unsigned short)f2bf(fmaxf(fmaf(acc, inv, sh), 0.f));
        }
    }
}

// ---------------------------------------------------------------------------
// k_attn: flash attention, S^T operand order (P writes = b64), 32 q/wave,
// m-tile 64, optional m-split with unnormalized partials (exact: no max-sub).
// block = 128 thr (2 waves), LDS 27.6 KB -> 4 blocks/CU with grid 1024.
// ---------------------------------------------------------------------------
__global__ __launch_bounds__(128) void k_attn(
    const unsigned short* __restrict__ xT, const unsigned short* __restrict__ vbf,
    float* __restrict__ outO, float* __restrict__ outL,
    int tilesPer, int normalize)
{
    __shared__ unsigned short Klds[64 * 72];        // [m][c]
    __shared__ unsigned short Vlds[64 * 72];        // [d][m]
    __shared__ unsigned short Plds[2][32 * 72];     // per-wave [n][m]

    const int ms  = blockIdx.x >> 9;
    const int b   = (blockIdx.x >> 6) & 7;
    const int q64 = blockIdx.x & 63;
    const int tid = threadIdx.x;
    const int wv = tid >> 6, lane = tid & 63;
    const int quad = lane >> 4, l4 = lane & 15;

    outO += (size_t)ms * (8u * 4096 * 64);
    outL += (size_t)ms * (8u * 4096);
    const int mt0 = ms * tilesPer, mt1 = mt0 + tilesPer;

    // Q fragments: 2 halves x 16 rows, held in registers for the whole kernel
    s16x8 A[2][2];
#pragma unroll
    for (int h = 0; h < 2; ++h) {
        const int4* qp = (const int4*)(xT +
            (((size_t)((b << 12) + (q64 << 6) + (wv << 5) + (h << 4) + l4)) << 6));
        CvtI4 c0, c1; c0.i = qp[quad]; c1.i = qp[4 + quad];
        A[h][0] = c0.s; A[h][1] = c1.s;
    }

    f32x4 O[2][4];
    float rs[2] = {0.f, 0.f};
#pragma unroll
    for (int h = 0; h < 2; ++h)
#pragma unroll
        for (int d = 0; d < 4; ++d) O[h][d] = (f32x4){0.f, 0.f, 0.f, 0.f};

    const int mr = tid >> 3, c8 = tid & 7;

    for (int mt = mt0; mt < mt1; ++mt) {
        const int m0 = mt << 6;
        __syncthreads();
#pragma unroll
        for (int it = 0; it < 4; ++it) {   // stage K rows + V rows (16B each)
            int m = (it << 4) + mr;
            *(int4*)(Klds + m * 72 + (c8 << 3)) =
                *(const int4*)(xT + (((size_t)((b << 12) + m0 + m)) << 6) + (c8 << 3));
            *(int4*)(Vlds + m * 72 + (c8 << 3)) =
                *(const int4*)(vbf + (((size_t)((b << 6) + m)) << 12) + m0 + (c8 << 3));
        }
        __syncthreads();

        unsigned short* Pw = Plds[wv];
        // S^T = K . Q^T : lane holds 4 consecutive m for one n -> b64 P write
#pragma unroll
        for (int msub = 0; msub < 4; ++msub) {
            const unsigned short* kr = Klds + ((msub << 4) + l4) * 72 + (quad << 3);
            const s16x8 K0 = *(const s16x8*)kr;
            const s16x8 K1 = *(const s16x8*)(kr + 32);
#pragma unroll
            for (int h = 0; h < 2; ++h) {
                f32x4 S = (f32x4){0.f, 0.f, 0.f, 0.f};
                S = __builtin_amdgcn_mfma_f32_16x16x32_bf16(K0, A[h][0], S, 0, 0, 0);
                S = __builtin_amdgcn_mfma_f32_16x16x32_bf16(K1, A[h][1], S, 0, 0, 0);
                float p0 = __builtin_amdgcn_exp2f(S[0]);
                float p1 = __builtin_amdgcn_exp2f(S[1]);
                float p2 = __builtin_amdgcn_exp2f(S[2]);
                float p3 = __builtin_amdgcn_exp2f(S[3]);
                rs[h] += (p0 + p1) + (p2 + p3);
                uint2 pk;
                pk.x = f2bf(p0) | (f2bf(p1) << 16);
                pk.y = f2bf(p2) | (f2bf(p3) << 16);
                *(uint2*)(Pw + ((h << 4) + l4) * 72 + (msub << 4) + (quad << 2)) = pk;
            }
        }
        // O += P . V^T
#pragma unroll
        for (int g = 0; g < 2; ++g) {
            s16x8 Ap[2];
#pragma unroll
            for (int h = 0; h < 2; ++h)
                Ap[h] = *(const s16x8*)(Pw + ((h << 4) + l4) * 72 + (g << 5) + (quad << 3));
#pragma unroll
            for (int dt = 0; dt < 4; ++dt) {
                const s16x8 Bv = *(const s16x8*)(Vlds + ((dt << 4) + l4) * 72 + (g << 5) + (quad << 3));
                O[0][dt] = __builtin_amdgcn_mfma_f32_16x16x32_bf16(Ap[0], Bv, O[0][dt], 0, 0, 0);
                O[1][dt] = __builtin_amdgcn_mfma_f32_16x16x32_bf16(Ap[1], Bv, O[1][dt], 0, 0, 0);
            }
        }
    }

    // denom: reduce across quads (all lanes end with full sum for n = l4)
    rs[0] += __shfl_xor(rs[0], 16); rs[0] += __shfl_xor(rs[0], 32);
    rs[1] += __shfl_xor(rs[1], 16); rs[1] += __shfl_xor(rs[1], 32);

    const int nb = (b << 12) + (q64 << 6) + (wv << 5);
    if (normalize) {
        float i0 = 1.f / rs[0], i1 = 1.f / rs[1];
#pragma unroll
        for (int h = 0; h < 2; ++h)
#pragma unroll
            for (int r = 0; r < 4; ++r) {
                int src = (lane & 48) | (quad << 2) | r;
                float inv = __shfl(h ? i1 : i0, src);
                float* row = outO + (((size_t)(nb + (h << 4) + (quad << 2) + r)) << 6) + l4;
#pragma unroll
                for (int dt = 0; dt < 4; ++dt) row[dt << 4] = O[h][dt][r] * inv;
            }
    } else {
#pragma unroll
        for (int h = 0; h < 2; ++h)
#pragma unroll
            for (int r = 0; r < 4; ++r) {
                float* row = outO + (((size_t)(nb + (h << 4) + (quad << 2) + r)) << 6) + l4;
#pragma unroll
                for (int dt = 0; dt < 4; ++dt) row[dt << 4] = O[h][dt][r];
            }
        if (quad == 0)      outL[nb + l4]      = rs[0];
        else if (quad == 1) outL[nb + 16 + l4] = rs[1];
    }
}

// ---------------------------------------------------------------------------
// k_post: combine partials + dwconv3x3 + BN2 + ReLU -> LDS tile ->
//         pointwise(w3) + BN3 + residual. grid 512 = (b, h), 256 thr.
// ---------------------------------------------------------------------------
__global__ __launch_bounds__(256) void k_post(
    const float* __restrict__ O1, const float* __restrict__ O2,
    const float* __restrict__ L1, const float* __restrict__ L2,
    const float* __restrict__ x,
    const float* __restrict__ w2,
    const float* __restrict__ g2, const float* __restrict__ b2,
    const float* __restrict__ m2, const float* __restrict__ v2,
    const float* __restrict__ w3,
    const float* __restrict__ g3, const float* __restrict__ b3,
    const float* __restrict__ m3, const float* __restrict__ v3,
    float* __restrict__ out, int nsplit)
{
    __shared__ float T[64 * 68];   // [w][c] pad
    const int b = blockIdx.x >> 6;
    const int h = blockIdx.x & 63;
    const int tid = threadIdx.x;
    const int w = tid & 63, cq = tid >> 6;

    float t16[16];
#pragma unroll
    for (int i = 0; i < 16; ++i) t16[i] = 0.f;

#pragma unroll
    for (int ky = 0; ky < 3; ++ky) {
        int hh = h + ky - 1;
        if (hh < 0 || hh > 63) continue;     // block-uniform
#pragma unroll
        for (int kx = 0; kx < 3; ++kx) {
            int ww = w + kx - 1;
            if (ww < 0 || ww > 63) continue; // divergent only at edge lanes
            int npos = (b << 12) + (hh << 6) + ww;
            const float* r1 = O1 + (((size_t)npos) << 6) + (cq << 4);
            float4 a[4];
#pragma unroll
            for (int i = 0; i < 4; ++i) a[i] = *(const float4*)(r1 + (i << 2));
            if (nsplit == 2) {
                const float* r2 = O2 + (((size_t)npos) << 6) + (cq << 4);
                float invd = 1.f / (L1[npos] + L2[npos]);
#pragma unroll
                for (int i = 0; i < 4; ++i) {
                    float4 a2 = *(const float4*)(r2 + (i << 2));
                    a[i].x = (a[i].x + a2.x) * invd;
                    a[i].y = (a[i].y + a2.y) * invd;
                    a[i].z = (a[i].z + a2.z) * invd;
                    a[i].w = (a[i].w + a2.w) * invd;
                }
            }
            const int k = ky * 3 + kx;
#pragma unroll
            for (int i = 0; i < 4; ++i) {
                int c = (cq << 4) + (i << 2);
                t16[i * 4 + 0] = fmaf(w2[(c + 0) * 9 + k], a[i].x, t16[i * 4 + 0]);
                t16[i * 4 + 1] = fmaf(w2[(c + 1) * 9 + k], a[i].y, t16[i * 4 + 1]);
                t16[i * 4 + 2] = fmaf(w2[(c + 2) * 9 + k], a[i].z, t16[i * 4 + 2]);
                t16[i * 4 + 3] = fmaf(w2[(c + 3) * 9 + k], a[i].w, t16[i * 4 + 3]);
            }
        }
    }
#pragma unroll
    for (int i = 0; i < 16; ++i) {
        int c = (cq << 4) + i;
        float inv = g2[c] * rsqrtf(v2[c] + 1e-5f);
        float sh  = b2[c] - m2[c] * inv;
        T[w * 68 + c] = fmaxf(fmaf(t16[i], inv, sh), 0.f);
    }
    __syncthreads();

    float rT[64];
#pragma unroll
    for (int c4 = 0; c4 < 16; ++c4)
        *(float4*)&rT[c4 << 2] = *(const float4*)&T[w * 68 + (c4 << 2)];

    const int hw = (h << 6) + w;
#pragma unroll 2
    for (int oo = 0; oo < 16; ++oo) {
        int o = (cq << 4) + oo;
        float inv = g3[o] * rsqrtf(v3[o] + 1e-5f);
        float sh  = b3[o] - m3[o] * inv;
        float acc = 0.f;
#pragma unroll
        for (int c = 0; c < 64; ++c) acc = fmaf(w3[o * 64 + c], rT[c], acc);
        size_t idx = (((size_t)((b << 6) + o)) << 12) + hw;
        out[idx] = fmaf(acc, inv, sh) + x[idx];
    }
}

// ---------------------------------------------------------------------------
extern "C" void kernel_launch(void* const* d_in, const int* in_sizes, int n_in,
                              void* d_out, int out_size, void* d_ws, size_t ws_size,
                              hipStream_t stream)
{
    const float* x  = (const float*)d_in[0];
    const float* w1 = (const float*)d_in[1];
    const float* g1 = (const float*)d_in[2];
    const float* b1 = (const float*)d_in[3];
    const float* m1 = (const float*)d_in[4];
    const float* v1 = (const float*)d_in[5];
    const float* w2 = (const float*)d_in[6];
    const float* g2 = (const float*)d_in[7];
    const float* b2 = (const float*)d_in[8];
    const float* m2 = (const float*)d_in[9];
    const float* v2 = (const float*)d_in[10];
    const float* w3 = (const float*)d_in[11];
    const float* g3 = (const float*)d_in[12];
    const float* b3 = (const float*)d_in[13];
    const float* m3 = (const float*)d_in[14];
    const float* v3 = (const float*)d_in[15];
    float* out = (float*)d_out;

    // ws: xT 4MB | vbf 4MB | O1 8MB | [O2 8MB | L1 128KB | L2 128KB]
    unsigned short* xT  = (unsigned short*)d_ws;
    unsigned short* vbf = xT + (size_t)8 * 4096 * 64;
    float* O1 = (float*)((char*)d_ws + (8u  << 20));
    float* O2 = (float*)((char*)d_ws + (16u << 20));
    float* L1 = (float*)((char*)d_ws + (24u << 20));
    float* L2 = L1 + 8 * 4096;

    const size_t need_split = (24u << 20) + 2u * 8 * 4096 * 4;
    const int nsplit = (ws_size >= need_split) ? 2 : 1;

    k_prep<<<512, 256, 0, stream>>>(x, w1, g1, b1, m1, v1, xT, vbf);
    k_attn<<<512 * nsplit, 128, 0, stream>>>(xT, vbf, O1, L1, 64 / nsplit, nsplit == 1);
    k_post<<<512, 256, 0, stream>>>(O1, O2, L1, L2, x, w2, g2, b2, m2, v2,
                                    w3, g3, b3, m3, v3, out, nsplit);
}

// Round 3
// 267.992 us; speedup vs baseline: 1.2141x; 1.0171x over previous
//
#include <hip/hip_runtime.h>
#include <stdint.h>

typedef __attribute__((ext_vector_type(8))) short s16x8;   // 8 x bf16
typedef __attribute__((ext_vector_type(4))) float f32x4;   // MFMA acc

union CvtI4 { int4 i; s16x8 s; };

__device__ __forceinline__ unsigned f2bf(float f) {
    union { float f; unsigned u; } v; v.f = f;
    return (v.u + 0x7fffu + ((v.u >> 16) & 1u)) >> 16;     // RNE
}

// ---------------------------------------------------------------------------
// k_prep: grid 1024 = (b, n0-chunk, half). LDS-transpose x tile ->
//   xT[b][n][c] = bf16(x * sqrt(log2e/8)), vbf[b][c][n] = bf16(relu(bn1(w1.x)))
// ---------------------------------------------------------------------------
__global__ __launch_bounds__(256) void k_prep(
    const float* __restrict__ x, const float* __restrict__ w1,
    const float* __restrict__ g1, const float* __restrict__ b1,
    const float* __restrict__ m1, const float* __restrict__ v1,
    unsigned short* __restrict__ xT, unsigned short* __restrict__ vbf)
{
    __shared__ float X[64 * 65];   // [c][n] pad+1
    const int b    = blockIdx.x >> 7;
    const int n0   = ((blockIdx.x >> 1) & 63) << 6;
    const int half = blockIdx.x & 1;
    const int tid  = threadIdx.x;
    const float QS = 0.42466090014400953f;   // sqrt(log2(e)/8)

    {   // coalesced load: wave = c rows, lanes = n
        const int r = tid >> 6, nn = tid & 63;
        const float* xb = x + (size_t)b * 262144 + n0 + nn;
#pragma unroll
        for (int cc = 0; cc < 16; ++cc) {
            int c = cc * 4 + r;
            X[c * 65 + nn] = xb[(size_t)c * 4096];
        }
    }
    __syncthreads();

    {   // xT: this half writes 32 n rows, 8 threads per 128B row
        const int n8 = tid >> 3, c8 = tid & 7;
        const int n = (half << 5) + n8;
        unsigned u[4];
#pragma unroll
        for (int j = 0; j < 4; ++j) {
            unsigned lo = f2bf(X[(c8 * 8 + 2 * j) * 65 + n] * QS);
            unsigned hi = f2bf(X[(c8 * 8 + 2 * j + 1) * 65 + n] * QS);
            u[j] = lo | (hi << 16);
        }
        uint4 pk; pk.x = u[0]; pk.y = u[1]; pk.z = u[2]; pk.w = u[3];
        *(uint4*)(xT + (((size_t)((b << 12) + n0 + n)) << 6) + (c8 << 3)) = pk;
    }

    {   // V = relu(bn1(conv1x1)): this half computes 32 output channels
        const int n = tid & 63, og = tid >> 6;
        float rX[64];
#pragma unroll
        for (int c = 0; c < 64; ++c) rX[c] = X[c * 65 + n];
        unsigned short* vb = vbf + (((size_t)(b << 6)) << 12) + n0 + n;
#pragma unroll 2
        for (int oo = 0; oo < 8; ++oo) {
            int o = (half << 5) + og * 8 + oo;
            float inv = g1[o] * rsqrtf(v1[o] + 1e-5f);
            float sh  = b1[o] - m1[o] * inv;
            float acc = 0.f;
#pragma unroll
            for (int c = 0; c < 64; ++c) acc = fmaf(w1[o * 64 + c], rX[c], acc);
            vb[(size_t)o << 12] = (unsigned short)f2bf(fmaxf(fmaf(acc, inv, sh), 0.f));
        }
    }
}

// ---------------------------------------------------------------------------
// k_attn v3: BARRIER-FREE flash attention.
// K/V fragments loaded directly from global (L1/L2-hot); only the per-wave
// P C-layout->A-layout round-trip uses LDS (wave-internal, no __syncthreads).
// Block = 4 independent waves, 32 q/wave, m-tile 64, m-split via grid.
// blockIdx = ((ms*8 + b) << 5) | qgrp.
// ---------------------------------------------------------------------------
__global__ __launch_bounds__(256, 4) void k_attn(
    const unsigned short* __restrict__ xT, const unsigned short* __restrict__ vbf,
    float* __restrict__ outO, float* __restrict__ outL,
    int tilesPer, int normalize)
{
    __shared__ unsigned short Plds[4][32 * 72];   // per-wave [n][m], pitch 72

    const int ms   = blockIdx.x >> 8;
    const int b    = (blockIdx.x >> 5) & 7;
    const int qgrp = blockIdx.x & 31;
    const int tid  = threadIdx.x;
    const int wv = tid >> 6, lane = tid & 63;
    const int quad = lane >> 4, l4 = lane & 15;

    outO += (size_t)ms * (8u * 4096 * 64);
    outL += (size_t)ms * (8u * 4096);

    const int qbase = (qgrp << 7) + (wv << 5);   // within batch b

    // Q fragments (held whole kernel): 2 halves x 16 rows
    s16x8 A[2][2];
#pragma unroll
    for (int h = 0; h < 2; ++h) {
        const int4* qp = (const int4*)(xT +
            (((size_t)((b << 12) + qbase + (h << 4) + l4)) << 6));
        CvtI4 c0, c1; c0.i = qp[quad]; c1.i = qp[4 + quad];
        A[h][0] = c0.s; A[h][1] = c1.s;
    }

    f32x4 O[2][4];
    float rs[2] = {0.f, 0.f};
#pragma unroll
    for (int h = 0; h < 2; ++h)
#pragma unroll
        for (int d = 0; d < 4; ++d) O[h][d] = (f32x4){0.f, 0.f, 0.f, 0.f};

    unsigned short* Pw = Plds[wv];
    const int mt0 = ms * tilesPer;

    for (int mt = 0; mt < tilesPer; ++mt) {
        const int m0 = (mt0 + mt) << 6;
        const unsigned short* Kb = xT + (((size_t)((b << 12) + m0)) << 6);

        // S^T = K . Q^T per 16-m subtile; P = exp2(S) -> LDS (A-layout rows)
#pragma unroll
        for (int msub = 0; msub < 4; ++msub) {
            const unsigned short* kr = Kb + (((msub << 4) + l4) << 6) + (quad << 3);
            const s16x8 K0 = *(const s16x8*)kr;
            const s16x8 K1 = *(const s16x8*)(kr + 32);
#pragma unroll
            for (int h = 0; h < 2; ++h) {
                f32x4 S = (f32x4){0.f, 0.f, 0.f, 0.f};
                S = __builtin_amdgcn_mfma_f32_16x16x32_bf16(K0, A[h][0], S, 0, 0, 0);
                S = __builtin_amdgcn_mfma_f32_16x16x32_bf16(K1, A[h][1], S, 0, 0, 0);
                float p0 = __builtin_amdgcn_exp2f(S[0]);
                float p1 = __builtin_amdgcn_exp2f(S[1]);
                float p2 = __builtin_amdgcn_exp2f(S[2]);
                float p3 = __builtin_amdgcn_exp2f(S[3]);
                rs[h] += (p0 + p1) + (p2 + p3);
                union { float f; unsigned u; } b0, b1c, b2c, b3c;
                b0.f = p0; b1c.f = p1; b2c.f = p2; b3c.f = p3;
                uint2 pk;   // cheap unbiased round-to-nearest bf16 pack
                pk.x = ((b0.u  + 0x8000u) >> 16) | ((b1c.u + 0x8000u) & 0xFFFF0000u);
                pk.y = ((b2c.u + 0x8000u) >> 16) | ((b3c.u + 0x8000u) & 0xFFFF0000u);
                *(uint2*)(Pw + ((h << 4) + l4) * 72 + (msub << 4) + (quad << 2)) = pk;
            }
        }
        // O += P . V^T, V fragments straight from global rows of vbf
#pragma unroll
        for (int g = 0; g < 2; ++g) {
            s16x8 Ap[2];
#pragma unroll
            for (int h = 0; h < 2; ++h)
                Ap[h] = *(const s16x8*)(Pw + ((h << 4) + l4) * 72 + (g << 5) + (quad << 3));
#pragma unroll
            for (int dt = 0; dt < 4; ++dt) {
                const s16x8 Bv = *(const s16x8*)(vbf +
                    (((size_t)((b << 6) + (dt << 4) + l4)) << 12) + m0 + (g << 5) + (quad << 3));
                O[0][dt] = __builtin_amdgcn_mfma_f32_16x16x32_bf16(Ap[0], Bv, O[0][dt], 0, 0, 0);
                O[1][dt] = __builtin_amdgcn_mfma_f32_16x16x32_bf16(Ap[1], Bv, O[1][dt], 0, 0, 0);
            }
        }
    }

    rs[0] += __shfl_xor(rs[0], 16); rs[0] += __shfl_xor(rs[0], 32);
    rs[1] += __shfl_xor(rs[1], 16); rs[1] += __shfl_xor(rs[1], 32);

    const int nb = (b << 12) + qbase;
    if (normalize) {
        float i0 = 1.f / rs[0], i1 = 1.f / rs[1];
#pragma unroll
        for (int h = 0; h < 2; ++h)
#pragma unroll
            for (int r = 0; r < 4; ++r) {
                int src = (lane & 48) | (quad << 2) | r;
                float inv = __shfl(h ? i1 : i0, src);
                float* row = outO + (((size_t)(nb + (h << 4) + (quad << 2) + r)) << 6) + l4;
#pragma unroll
                for (int dt = 0; dt < 4; ++dt) row[dt << 4] = O[h][dt][r] * inv;
            }
    } else {
#pragma unroll
        for (int h = 0; h < 2; ++h)
#pragma unroll
            for (int r = 0; r < 4; ++r) {
                float* row = outO + (((size_t)(nb + (h << 4) + (quad << 2) + r)) << 6) + l4;
#pragma unroll
                for (int dt = 0; dt < 4; ++dt) row[dt << 4] = O[h][dt][r];
            }
        if (quad == 0)      outL[nb + l4]      = rs[0];
        else if (quad == 1) outL[nb + 16 + l4] = rs[1];
    }
}

// ---------------------------------------------------------------------------
// k_post: stage 3-row window (combining nsplit partials) into LDS ->
// dwconv3x3 + BN2 + ReLU -> LDS -> pointwise(w3) + BN3 + residual.
// grid 512 = (b, h), 256 thr.
// ---------------------------------------------------------------------------
__global__ __launch_bounds__(256) void k_post(
    const float* __restrict__ Obase, const float* __restrict__ Lbase,
    const float* __restrict__ x,
    const float* __restrict__ w2,
    const float* __restrict__ g2, const float* __restrict__ b2,
    const float* __restrict__ m2, const float* __restrict__ v2,
    const float* __restrict__ w3,
    const float* __restrict__ g3, const float* __restrict__ b3,
    const float* __restrict__ m3, const float* __restrict__ v3,
    float* __restrict__ out, int nsplit, int normalized)
{
    __shared__ float W[3][64 * 66];   // combined attn window [row][w][c]
    __shared__ float T2[64 * 66];     // post-dwconv activations [w][c]

    const int b = blockIdx.x >> 6;
    const int h = blockIdx.x & 63;
    const int tid = threadIdx.x;

    // stage + combine partials
#pragma unroll
    for (int r = 0; r < 3; ++r) {
        int hh = h + r - 1;
        if (hh >= 0 && hh <= 63) {
#pragma unroll
            for (int i = 0; i < 4; ++i) {
                int lin = (i << 8) + tid;            // 1024 float4 groups
                int w = lin >> 4, cg = lin & 15;
                size_t npos = (size_t)((b << 12) + (hh << 6) + w);
                const float* p0 = Obase + (npos << 6) + (cg << 2);
                float4 a = *(const float4*)p0;
                float sl = normalized ? 0.f : Lbase[npos];
                for (int s = 1; s < nsplit; ++s) {
                    const float4 a2 = *(const float4*)(p0 + (size_t)s * 2097152);
                    a.x += a2.x; a.y += a2.y; a.z += a2.z; a.w += a2.w;
                    sl += Lbase[npos + (size_t)s * 32768];
                }
                float invd = normalized ? 1.f : 1.f / sl;
                a.x *= invd; a.y *= invd; a.z *= invd; a.w *= invd;
                *(float4*)&W[r][w * 66 + (cg << 2)] = a;
            }
        } else {
            float4 z = {0.f, 0.f, 0.f, 0.f};
#pragma unroll
            for (int i = 0; i < 4; ++i) {
                int lin = (i << 8) + tid;
                *(float4*)&W[r][(lin >> 4) * 66 + ((lin & 15) << 2)] = z;
            }
        }
    }
    __syncthreads();

    // dwconv 3x3 + BN2 + ReLU, thread = (w, 16-channel group)
    const int w = tid & 63, cq = tid >> 6;
    float t16[16];
#pragma unroll
    for (int i = 0; i < 16; ++i) t16[i] = 0.f;

#pragma unroll
    for (int ky = 0; ky < 3; ++ky) {
#pragma unroll
        for (int kx = 0; kx < 3; ++kx) {
            int ww = w + kx - 1;
            if (ww < 0 || ww > 63) continue;
            const int k = ky * 3 + kx;
            const float* Wr = &W[ky][ww * 66 + (cq << 4)];
#pragma unroll
            for (int i = 0; i < 4; ++i) {
                float4 a = *(const float4*)(Wr + (i << 2));
                int c = (cq << 4) + (i << 2);
                t16[i * 4 + 0] = fmaf(w2[(c + 0) * 9 + k], a.x, t16[i * 4 + 0]);
                t16[i * 4 + 1] = fmaf(w2[(c + 1) * 9 + k], a.y, t16[i * 4 + 1]);
                t16[i * 4 + 2] = fmaf(w2[(c + 2) * 9 + k], a.z, t16[i * 4 + 2]);
                t16[i * 4 + 3] = fmaf(w2[(c + 3) * 9 + k], a.w, t16[i * 4 + 3]);
            }
        }
    }
#pragma unroll
    for (int i = 0; i < 16; ++i) {
        int c = (cq << 4) + i;
        float inv = g2[c] * rsqrtf(v2[c] + 1e-5f);
        float sh  = b2[c] - m2[c] * inv;
        T2[w * 66 + c] = fmaxf(fmaf(t16[i], inv, sh), 0.f);
    }
    __syncthreads();

    float rT[64];
#pragma unroll
    for (int c4 = 0; c4 < 16; ++c4)
        *(float4*)&rT[c4 << 2] = *(const float4*)&T2[w * 66 + (c4 << 2)];

    const int hw = (h << 6) + w;
#pragma unroll 2
    for (int oo = 0; oo < 16; ++oo) {
        int o = (cq << 4) + oo;
        float inv = g3[o] * rsqrtf(v3[o] + 1e-5f);
        float sh  = b3[o] - m3[o] * inv;
        float acc = 0.f;
#pragma unroll
        for (int c = 0; c < 64; ++c) acc = fmaf(w3[o * 64 + c], rT[c], acc);
        size_t idx = (((size_t)((b << 6) + o)) << 12) + hw;
        out[idx] = fmaf(acc, inv, sh) + x[idx];
    }
}

// ---------------------------------------------------------------------------
extern "C" void kernel_launch(void* const* d_in, const int* in_sizes, int n_in,
                              void* d_out, int out_size, void* d_ws, size_t ws_size,
                              hipStream_t stream)
{
    const float* x  = (const float*)d_in[0];
    const float* w1 = (const float*)d_in[1];
    const float* g1 = (const float*)d_in[2];
    const float* b1 = (const float*)d_in[3];
    const float* m1 = (const float*)d_in[4];
    const float* v1 = (const float*)d_in[5];
    const float* w2 = (const float*)d_in[6];
    const float* g2 = (const float*)d_in[7];
    const float* b2 = (const float*)d_in[8];
    const float* m2 = (const float*)d_in[9];
    const float* v2 = (const float*)d_in[10];
    const float* w3 = (const float*)d_in[11];
    const float* g3 = (const float*)d_in[12];
    const float* b3 = (const float*)d_in[13];
    const float* m3 = (const float*)d_in[14];
    const float* v3 = (const float*)d_in[15];
    float* out = (float*)d_out;

    // ws: xT 4MB | vbf 4MB | O_s nsplit*8MB | L_s nsplit*128KB
    unsigned short* xT  = (unsigned short*)d_ws;
    unsigned short* vbf = xT + (size_t)8 * 4096 * 64;
    float* Obase = (float*)((char*)d_ws + (8u << 20));

    const size_t need4 = (8u << 20) + 4u * ((8u << 20) + (128u << 10));
    const size_t need2 = (8u << 20) + 2u * ((8u << 20) + (128u << 10));
    const int nsplit = (ws_size >= need4) ? 4 : (ws_size >= need2 ? 2 : 1);
    float* Lbase = Obase + (size_t)nsplit * 2097152;

    k_prep<<<1024, 256, 0, stream>>>(x, w1, g1, b1, m1, v1, xT, vbf);
    k_attn<<<256 * nsplit, 256, 0, stream>>>(xT, vbf, Obase, Lbase,
                                             64 / nsplit, nsplit == 1);
    k_post<<<512, 256, 0, stream>>>(Obase, Lbase, x, w2, g2, b2, m2, v2,
                                    w3, g3, b3, m3, v3, out, nsplit, nsplit == 1);
}

// Round 4
// 231.796 us; speedup vs baseline: 1.4037x; 1.1562x over previous
//
#include <hip/hip_runtime.h>
#include <stdint.h>

typedef __attribute__((ext_vector_type(8)))  short s16x8;   // 8 x bf16
typedef __attribute__((ext_vector_type(16))) float f32x16;  // 32x32 MFMA acc

union CvtI4 { int4 i; s16x8 s; };

__device__ __forceinline__ unsigned f2bf(float f) {
    union { float f; unsigned u; } v; v.f = f;
    return (v.u + 0x7fffu + ((v.u >> 16) & 1u)) >> 16;     // RNE
}

// ---------------------------------------------------------------------------
// k_prep: grid 1024 = (b, n0-chunk, half). LDS-transpose x tile ->
//   xT[b][n][c] = bf16(x * sqrt(log2e/8)), vbf[b][c][n] = bf16(relu(bn1(w1.x)))
// ---------------------------------------------------------------------------
__global__ __launch_bounds__(256) void k_prep(
    const float* __restrict__ x, const float* __restrict__ w1,
    const float* __restrict__ g1, const float* __restrict__ b1,
    const float* __restrict__ m1, const float* __restrict__ v1,
    unsigned short* __restrict__ xT, unsigned short* __restrict__ vbf)
{
    __shared__ float X[64 * 65];   // [c][n] pad+1
    const int b    = blockIdx.x >> 7;
    const int n0   = ((blockIdx.x >> 1) & 63) << 6;
    const int half = blockIdx.x & 1;
    const int tid  = threadIdx.x;
    const float QS = 0.42466090014400953f;   // sqrt(log2(e)/8)

    {
        const int r = tid >> 6, nn = tid & 63;
        const float* xb = x + (size_t)b * 262144 + n0 + nn;
#pragma unroll
        for (int cc = 0; cc < 16; ++cc) {
            int c = cc * 4 + r;
            X[c * 65 + nn] = xb[(size_t)c * 4096];
        }
    }
    __syncthreads();

    {   // xT: 32 n rows, 8 threads per 128B row
        const int n8 = tid >> 3, c8 = tid & 7;
        const int n = (half << 5) + n8;
        unsigned u[4];
#pragma unroll
        for (int j = 0; j < 4; ++j) {
            unsigned lo = f2bf(X[(c8 * 8 + 2 * j) * 65 + n] * QS);
            unsigned hi = f2bf(X[(c8 * 8 + 2 * j + 1) * 65 + n] * QS);
            u[j] = lo | (hi << 16);
        }
        uint4 pk; pk.x = u[0]; pk.y = u[1]; pk.z = u[2]; pk.w = u[3];
        *(uint4*)(xT + (((size_t)((b << 12) + n0 + n)) << 6) + (c8 << 3)) = pk;
    }

    {   // V = relu(bn1(conv1x1)): 32 output channels for this half
        const int n = tid & 63, og = tid >> 6;
        float rX[64];
#pragma unroll
        for (int c = 0; c < 64; ++c) rX[c] = X[c * 65 + n];
        unsigned short* vb = vbf + (((size_t)(b << 6)) << 12) + n0 + n;
#pragma unroll 2
        for (int oo = 0; oo < 8; ++oo) {
            int o = (half << 5) + og * 8 + oo;
            float inv = g1[o] * rsqrtf(v1[o] + 1e-5f);
            float sh  = b1[o] - m1[o] * inv;
            float acc = 0.f;
#pragma unroll
            for (int c = 0; c < 64; ++c) acc = fmaf(w1[o * 64 + c], rX[c], acc);
            vb[(size_t)o << 12] = (unsigned short)f2bf(fmaxf(fmaf(acc, inv, sh), 0.f));
        }
    }
}

// ---------------------------------------------------------------------------
// k_attn v4: 32x32x16 MFMA, cooperative 64q x 128m tiles, swizzled LDS.
//   S^T = K.Q^T  (A=K rows, B=Q rows; C/D: col=n=lane&31,
//                 row=m=(reg&3)+8*(reg>>2)+4*(lane>>5))
//   O   = P.V^T  (A=P[n][m] rows, B=V[d][m] rows)
// LDS tiles stored in 16B chunks at position (chunk ^ (row & mask)) to kill
// the 128/256B row-stride bank conflicts of fragment reads.
// grid = nsplit*512, 256 thr; XCD-aware decode keeps each XCD's K/V in L2.
// ---------------------------------------------------------------------------
__global__ __launch_bounds__(256) void k_attn(
    const unsigned short* __restrict__ xT, const unsigned short* __restrict__ vbf,
    float* __restrict__ outO, float* __restrict__ outL,
    int tilesPer, int nsplit)
{
    __shared__ __align__(16) unsigned short Klds[128 * 64];   // [m][c] swz8
    __shared__ __align__(16) unsigned short Vlds[64 * 128];   // [d][m] swz16
    __shared__ __align__(16) unsigned short Plds[64 * 128];   // [n][m] swz16
    __shared__ float rsLds[4][2][32];
    __shared__ float denomT[64];

    const int xcd  = blockIdx.x & 7;
    const int slot = blockIdx.x >> 3;
    const int qgrp = slot & 63;
    const int pair = xcd * nsplit + (slot >> 6);
    const int b = pair & 7;
    const int ms = pair >> 3;

    const int tid = threadIdx.x;
    const int w = tid >> 6, lane = tid & 63;
    const int l31 = lane & 31, half = lane >> 5;
    const int qbase = qgrp << 6;

    outO += (size_t)ms * 2097152u;
    outL += (size_t)ms * 32768u;

    // Q B-fragments held whole kernel: Bq[n32][kk], B[k=c][j=n]
    s16x8 Bq[2][4];
#pragma unroll
    for (int n32 = 0; n32 < 2; ++n32) {
        const unsigned short* qr = xT +
            (((size_t)((b << 12) + qbase + (n32 << 5) + l31)) << 6) + (half << 3);
#pragma unroll
        for (int kk = 0; kk < 4; ++kk) {
            CvtI4 c; c.i = *(const int4*)(qr + (kk << 4));
            Bq[n32][kk] = c.s;
        }
    }

    f32x16 O = {0.f,0.f,0.f,0.f,0.f,0.f,0.f,0.f,0.f,0.f,0.f,0.f,0.f,0.f,0.f,0.f};
    float rs0 = 0.f, rs1 = 0.f;
    const int mt0 = ms * tilesPer;

    for (int mt = 0; mt < tilesPer; ++mt) {
        const int m0 = (mt0 + mt) << 7;
        __syncthreads();   // prev PV/QK reads done before restage
#pragma unroll
        for (int it = 0; it < 4; ++it) {
            int lin = (it << 8) + tid;
            {   // K: 128 rows x 128B, chunk swizzle ^ (m&7)
                int km = lin >> 3, c4 = lin & 7;
                int4 d = *(const int4*)(xT + (((size_t)((b << 12) + m0 + km)) << 6) + (c4 << 3));
                *(int4*)(Klds + (km << 6) + ((c4 ^ (km & 7)) << 3)) = d;
            }
            {   // V: 64 rows x 256B, chunk swizzle ^ (d&15)
                int vd = lin >> 4, c16 = lin & 15;
                int4 d = *(const int4*)(vbf + (((size_t)((b << 6) + vd)) << 12) + m0 + (c16 << 3));
                *(int4*)(Vlds + (vd << 7) + ((c16 ^ (vd & 15)) << 3)) = d;
            }
        }
        __syncthreads();

        // A-frags: K rows m = w*32 + l31 (this wave's m-strip)
        const int km = (w << 5) + l31;
        s16x8 Ak[4];
#pragma unroll
        for (int kk = 0; kk < 4; ++kk) {
            int pos = ((kk << 1) + half) ^ (km & 7);
            Ak[kk] = *(const s16x8*)(Klds + (km << 6) + (pos << 3));
        }

#pragma unroll
        for (int n32 = 0; n32 < 2; ++n32) {
            f32x16 S = {0.f,0.f,0.f,0.f,0.f,0.f,0.f,0.f,0.f,0.f,0.f,0.f,0.f,0.f,0.f,0.f};
#pragma unroll
            for (int kk = 0; kk < 4; ++kk)
                S = __builtin_amdgcn_mfma_f32_32x32x16_bf16(Ak[kk], Bq[n32][kk], S, 0, 0, 0);
            const int nrow = (n32 << 5) + l31;
            float rsl = 0.f;
#pragma unroll
            for (int q = 0; q < 4; ++q) {
                float p0 = __builtin_amdgcn_exp2f(S[4*q+0]);
                float p1 = __builtin_amdgcn_exp2f(S[4*q+1]);
                float p2 = __builtin_amdgcn_exp2f(S[4*q+2]);
                float p3 = __builtin_amdgcn_exp2f(S[4*q+3]);
                rsl += (p0 + p1) + (p2 + p3);
                union { float f; unsigned u; } a0, a1, a2, a3;
                a0.f = p0; a1.f = p1; a2.f = p2; a3.f = p3;
                uint2 pk;
                pk.x = ((a0.u + 0x8000u) >> 16) | ((a1.u + 0x8000u) & 0xFFFF0000u);
                pk.y = ((a2.u + 0x8000u) >> 16) | ((a3.u + 0x8000u) & 0xFFFF0000u);
                int c16 = (w << 2) + q;               // m-chunk = (w*32+8q)/8
                *(uint2*)(Plds + (nrow << 7) + ((c16 ^ (nrow & 15)) << 3) + (half << 2)) = pk;
            }
            if (n32) rs1 += rsl; else rs0 += rsl;
        }
        __syncthreads();

        // PV: this wave owns O tile (n32 = w>>1, d32 = w&1), full m range
        const int nrow = ((w >> 1) << 5) + l31;
        const int drow = ((w & 1) << 5) + l31;
#pragma unroll
        for (int ks = 0; ks < 8; ++ks) {
            int c = (ks << 1) + half;
            const s16x8 Ap = *(const s16x8*)(Plds + (nrow << 7) + ((c ^ (nrow & 15)) << 3));
            const s16x8 Bv = *(const s16x8*)(Vlds + (drow << 7) + ((c ^ (drow & 15)) << 3));
            O = __builtin_amdgcn_mfma_f32_32x32x16_bf16(Ap, Bv, O, 0, 0, 0);
        }
    }

    // denominators: lane-halves hold same n -> fold, then cross-wave via LDS
    rs0 += __shfl_xor(rs0, 32);
    rs1 += __shfl_xor(rs1, 32);
    if (half == 0) { rsLds[w][0][l31] = rs0; rsLds[w][1][l31] = rs1; }
    __syncthreads();
    if (tid < 64) {
        int t = tid >> 5, n = tid & 31;
        denomT[tid] = ((rsLds[0][t][n] + rsLds[1][t][n]) +
                       (rsLds[2][t][n] + rsLds[3][t][n]));
    }
    __syncthreads();

    const int nb = (b << 12) + qbase;
    const int n32o = w >> 1, d32 = w & 1;
    if (nsplit == 1) {
#pragma unroll
        for (int r = 0; r < 16; ++r) {
            int nl = (r & 3) + ((r >> 2) << 3) + (half << 2);
            int n = (n32o << 5) + nl;
            float inv = 1.f / denomT[n];
            outO[((size_t)(nb + n) << 6) + (d32 << 5) + l31] = O[r] * inv;
        }
    } else {
#pragma unroll
        for (int r = 0; r < 16; ++r) {
            int nl = (r & 3) + ((r >> 2) << 3) + (half << 2);
            int n = (n32o << 5) + nl;
            outO[((size_t)(nb + n) << 6) + (d32 << 5) + l31] = O[r];
        }
        if (tid < 64) outL[nb + tid] = denomT[tid];
    }
}

// ---------------------------------------------------------------------------
// k_post: stage 3-row window (combining nsplit partials) into LDS ->
// dwconv3x3 + BN2 + ReLU -> LDS -> pointwise(w3) + BN3 + residual.
// grid 512 = (b, h), 256 thr.
// ---------------------------------------------------------------------------
__global__ __launch_bounds__(256) void k_post(
    const float* __restrict__ Obase, const float* __restrict__ Lbase,
    const float* __restrict__ x,
    const float* __restrict__ w2,
    const float* __restrict__ g2, const float* __restrict__ b2,
    const float* __restrict__ m2, const float* __restrict__ v2,
    const float* __restrict__ w3,
    const float* __restrict__ g3, const float* __restrict__ b3,
    const float* __restrict__ m3, const float* __restrict__ v3,
    float* __restrict__ out, int nsplit, int normalized)
{
    __shared__ float W[3][64 * 66];
    __shared__ float T2[64 * 66];

    const int b = blockIdx.x >> 6;
    const int h = blockIdx.x & 63;
    const int tid = threadIdx.x;

#pragma unroll
    for (int r = 0; r < 3; ++r) {
        int hh = h + r - 1;
        if (hh >= 0 && hh <= 63) {
#pragma unroll
            for (int i = 0; i < 4; ++i) {
                int lin = (i << 8) + tid;
                int w = lin >> 4, cg = lin & 15;
                size_t npos = (size_t)((b << 12) + (hh << 6) + w);
                const float* p0 = Obase + (npos << 6) + (cg << 2);
                float4 a = *(const float4*)p0;
                float sl = normalized ? 0.f : Lbase[npos];
                for (int s = 1; s < nsplit; ++s) {
                    const float4 a2 = *(const float4*)(p0 + (size_t)s * 2097152);
                    a.x += a2.x; a.y += a2.y; a.z += a2.z; a.w += a2.w;
                    sl += Lbase[npos + (size_t)s * 32768];
                }
                float invd = normalized ? 1.f : 1.f / sl;
                a.x *= invd; a.y *= invd; a.z *= invd; a.w *= invd;
                *(float4*)&W[r][w * 66 + (cg << 2)] = a;
            }
        } else {
            float4 z = {0.f, 0.f, 0.f, 0.f};
#pragma unroll
            for (int i = 0; i < 4; ++i) {
                int lin = (i << 8) + tid;
                *(float4*)&W[r][(lin >> 4) * 66 + ((lin & 15) << 2)] = z;
            }
        }
    }
    __syncthreads();

    const int w = tid & 63, cq = tid >> 6;
    float t16[16];
#pragma unroll
    for (int i = 0; i < 16; ++i) t16[i] = 0.f;

#pragma unroll
    for (int ky = 0; ky < 3; ++ky) {
#pragma unroll
        for (int kx = 0; kx < 3; ++kx) {
            int ww = w + kx - 1;
            if (ww < 0 || ww > 63) continue;
            const int k = ky * 3 + kx;
            const float* Wr = &W[ky][ww * 66 + (cq << 4)];
#pragma unroll
            for (int i = 0; i < 4; ++i) {
                float4 a = *(const float4*)(Wr + (i << 2));
                int c = (cq << 4) + (i << 2);
                t16[i * 4 + 0] = fmaf(w2[(c + 0) * 9 + k], a.x, t16[i * 4 + 0]);
                t16[i * 4 + 1] = fmaf(w2[(c + 1) * 9 + k], a.y, t16[i * 4 + 1]);
                t16[i * 4 + 2] = fmaf(w2[(c + 2) * 9 + k], a.z, t16[i * 4 + 2]);
                t16[i * 4 + 3] = fmaf(w2[(c + 3) * 9 + k], a.w, t16[i * 4 + 3]);
            }
        }
    }
#pragma unroll
    for (int i = 0; i < 16; ++i) {
        int c = (cq << 4) + i;
        float inv = g2[c] * rsqrtf(v2[c] + 1e-5f);
        float sh  = b2[c] - m2[c] * inv;
        T2[w * 66 + c] = fmaxf(fmaf(t16[i], inv, sh), 0.f);
    }
    __syncthreads();

    float rT[64];
#pragma unroll
    for (int c4 = 0; c4 < 16; ++c4)
        *(float4*)&rT[c4 << 2] = *(const float4*)&T2[w * 66 + (c4 << 2)];

    const int hw = (h << 6) + w;
#pragma unroll 2
    for (int oo = 0; oo < 16; ++oo) {
        int o = (cq << 4) + oo;
        float inv = g3[o] * rsqrtf(v3[o] + 1e-5f);
        float sh  = b3[o] - m3[o] * inv;
        float acc = 0.f;
#pragma unroll
        for (int c = 0; c < 64; ++c) acc = fmaf(w3[o * 64 + c], rT[c], acc);
        size_t idx = (((size_t)((b << 6) + o)) << 12) + hw;
        out[idx] = fmaf(acc, inv, sh) + x[idx];
    }
}

// ---------------------------------------------------------------------------
extern "C" void kernel_launch(void* const* d_in, const int* in_sizes, int n_in,
                              void* d_out, int out_size, void* d_ws, size_t ws_size,
                              hipStream_t stream)
{
    const float* x  = (const float*)d_in[0];
    const float* w1 = (const float*)d_in[1];
    const float* g1 = (const float*)d_in[2];
    const float* b1 = (const float*)d_in[3];
    const float* m1 = (const float*)d_in[4];
    const float* v1 = (const float*)d_in[5];
    const float* w2 = (const float*)d_in[6];
    const float* g2 = (const float*)d_in[7];
    const float* b2 = (const float*)d_in[8];
    const float* m2 = (const float*)d_in[9];
    const float* v2 = (const float*)d_in[10];
    const float* w3 = (const float*)d_in[11];
    const float* g3 = (const float*)d_in[12];
    const float* b3 = (const float*)d_in[13];
    const float* m3 = (const float*)d_in[14];
    const float* v3 = (const float*)d_in[15];
    float* out = (float*)d_out;

    // ws: xT 4MB | vbf 4MB | O_s nsplit*8MB | L_s nsplit*128KB
    unsigned short* xT  = (unsigned short*)d_ws;
    unsigned short* vbf = xT + (size_t)8 * 4096 * 64;
    float* Obase = (float*)((char*)d_ws + (8u << 20));

    const size_t need2 = (8u << 20) + 2u * ((8u << 20) + (128u << 10));
    const int nsplit = (ws_size >= need2) ? 2 : 1;
    float* Lbase = Obase + (size_t)nsplit * 2097152;

    k_prep<<<1024, 256, 0, stream>>>(x, w1, g1, b1, m1, v1, xT, vbf);
    k_attn<<<nsplit * 512, 256, 0, stream>>>(xT, vbf, Obase, Lbase,
                                             32 / nsplit, nsplit);
    k_post<<<512, 256, 0, stream>>>(Obase, Lbase, x, w2, g2, b2, m2, v2,
                                    w3, g3, b3, m3, v3, out, nsplit, nsplit == 1);
}